// Round 1
// 587.624 us; speedup vs baseline: 1.0192x; 1.0192x over previous
//
#include <hip/hip_runtime.h>
#include <stdint.h>

#define OUTSZ  (32*128*64*64)  // 16777216 elements per output tensor

typedef short bf16x8 __attribute__((ext_vector_type(8)));  // 8 bf16 = 4 VGPRs
typedef float f32x4  __attribute__((ext_vector_type(4)));

__device__ __forceinline__ uint16_t f2bf(float f) {
  union { float f; uint32_t u; } v; v.f = f;
  uint32_t u = v.u;
  u += 0x7fffu + ((u >> 16) & 1u);   // round-to-nearest-even
  return (uint16_t)(u >> 16);
}

__device__ __forceinline__ float sigf(float x) {
  return __builtin_amdgcn_rcpf(1.f + __expf(-x));
}
// tanh(x) = 2*sigmoid(2x) - 1: 5 VALU ops (mul, exp, add, rcp, fma) vs 8 for
// the abs/copysign form. Saturates correctly: exp(-2x)->inf => rcp->0 => -1;
// exp(-2x)->0 => +1. No NaN paths for finite input.
__device__ __forceinline__ float tanh2s(float x) {
  float e = __expf(-2.f * x);
  return __builtin_amdgcn_rcpf(1.f + e) * 2.f - 1.f;
}

// ---------------------------------------------------------------------------
// Kernel 1: x [B,C,H,W] fp32 -> x_nhwc [B,H,W,C] bf16   (one block per (b,h))
// ---------------------------------------------------------------------------
__global__ void transpose_x(const float* __restrict__ x, uint16_t* __restrict__ xn) {
  const int h = blockIdx.x, b = blockIdx.y;
  __shared__ float tile[128][65];
  const int tid = threadIdx.x;
  #pragma unroll
  for (int it = 0; it < 32; ++it) {
    int idx = it * 256 + tid;
    int c = idx >> 6, w = idx & 63;
    tile[c][w] = x[(((b * 128 + c) * 64 + h) << 6) + w];  // coalesced in w
  }
  __syncthreads();
  uint32_t* out = (uint32_t*)(xn + ((size_t)(b * 64 + h) * 64) * 128);
  #pragma unroll
  for (int it = 0; it < 16; ++it) {
    int idx = it * 256 + tid;
    int w = idx >> 6, cd = idx & 63;            // cd = pair of channels
    uint32_t lo = f2bf(tile[cd * 2][w]);
    uint32_t hi = f2bf(tile[cd * 2 + 1][w]);
    out[w * 64 + cd] = lo | (hi << 16);          // coalesced in c
  }
}

// ---------------------------------------------------------------------------
// Kernel 2: convert 8 LSTM [512x128] + 4 conv [128x128] weight mats to bf16
// ---------------------------------------------------------------------------
struct PrepArgs { const float* s[12]; };

__global__ void prep_weights(PrepArgs a, uint16_t* __restrict__ wbuf,
                             uint16_t* __restrict__ wcbuf) {
  int idx = blockIdx.x * 256 + threadIdx.x;
  if (idx < 524288) {
    int m = idx >> 16;
    wbuf[idx] = f2bf(a.s[m][idx & 65535]);
  } else {
    int j = idx - 524288;
    if (j < 65536) {
      int m = j >> 14;
      wcbuf[j] = f2bf(a.s[8 + m][j & 16383]);
    }
  }
}

// ---------------------------------------------------------------------------
// Kernel 3: fused bidirectional LSTM over both axes.
//   grid (64, 4): blockIdx.y = dir {0:v_fwd, 1:v_bwd, 2:h_fwd, 3:h_bwd}
//   512 thr = 8 waves, 32 sequences/block, full time loop in-block.
//
//   Pipelined restructure vs previous version:
//   - acc is initialized to bias and pre-accumulated with the ih projection
//     (x(t)@Wih) at the END of step t-1, overlapping the gate-math VALU/TRANS
//     phase (ih has no dependence on h). The barrier-locked critical path per
//     step is now only the 4-deep hh MFMA chain + gate math.
//   - __syncthreads() replaced by s_waitcnt lgkmcnt(0) + s_barrier: only LDS
//     ordering is required at the barrier. The dump store has no in-kernel
//     consumer and prefetch loads feed only the issuing wave, so the implicit
//     vmcnt(0)/expcnt(0) drain of __syncthreads was pure per-step overhead.
// ---------------------------------------------------------------------------
__global__ __launch_bounds__(512, 2) void lstm_kernel(
    const uint16_t* __restrict__ xn,    // [PIXTOT][128] bf16 NHWC
    const uint16_t* __restrict__ wbuf,  // 8 x [512][128] bf16
    const float* __restrict__ bvf, const float* __restrict__ bvb,
    const float* __restrict__ bhf, const float* __restrict__ bhb,
    uint16_t* __restrict__ hbuf)        // 4 x [2048*64][128] bf16
{
  const int dir  = blockIdx.y;
  const int seq0 = blockIdx.x * 32;
  const int tid  = threadIdx.x;
  const int wv   = tid >> 6;
  const int lane = tid & 63;
  const int l15  = lane & 15;
  const int l4   = lane >> 4;
  const int mycol = wv * 16 + l15;       // channel 0..127 this lane owns in C/D
  const bool rev   = (dir & 1);
  const bool horiz = (dir >= 2);

  const uint16_t* wih = wbuf + (size_t)(2 * dir) * (512 * 128);
  const uint16_t* whh = wih + 512 * 128;
  const float* bias = (dir == 0) ? bvf : (dir == 1) ? bvb : (dir == 2) ? bhf : bhb;
  uint16_t* hout = hbuf + (size_t)dir * ((size_t)2048 * 64 * 128);

  // B fragments: Wih/Whh are [4C][C] row-major = B^T; frag = 8 consecutive c.
  bf16x8 Bih[4][4], Bhh[4][4];           // [gate i/f/g/o][k-chunk]
  {
    const int base = mycol * 128 + l4 * 8;
    #pragma unroll
    for (int g = 0; g < 4; ++g)
      #pragma unroll
      for (int kc = 0; kc < 4; ++kc) {
        Bih[g][kc] = *(const bf16x8*)(wih + base + g * (128 * 128) + kc * 32);
        Bhh[g][kc] = *(const bf16x8*)(whh + base + g * (128 * 128) + kc * 32);
      }
  }
  float bia[4];
  #pragma unroll
  for (int g = 0; g < 4; ++g) bia[g] = bias[mycol + 128 * g];

  // 8-slot h ring. Row stride 136 u16 = 272B (16B aligned). 16B chunks are
  // XOR-swizzled by (row>>2)&3 -> scalar gate writes are bank-conflict-free.
  __shared__ __attribute__((aligned(16))) uint16_t ring[8][32][136];
  {
    uint32_t* p = (uint32_t*)&ring[7][0][0];   // only slot 7 is read at step 0
    for (int i = tid; i < 2176; i += 512) p[i] = 0;
  }
  __syncthreads();

  int xbase[2];
  #pragma unroll
  for (int mt = 0; mt < 2; ++mt) {
    int seq = seq0 + mt * 16 + l15;
    xbase[mt] = horiz ? (((seq >> 6) * 4096 + (seq & 63)) * 128)
                      : (seq * (64 * 128));
  }
  const int tstride = horiz ? (64 * 128) : 128;

  float cst[2][4];
  #pragma unroll
  for (int mt = 0; mt < 2; ++mt)
    #pragma unroll
    for (int r = 0; r < 4; ++r) cst[mt][r] = 0.f;

  // lazy-dump lane mapping: 512 thr cover one slot (32 rows x 16 chunks)
  const int drow   = tid >> 4;          // 0..31
  const int dchunk = tid & 15;
  const int dpc8   = dchunk ^ ((drow >> 2) & 3);

  auto dump_slot = [&](int g, int s) {
    bf16x8 v = *(const bf16x8*)(&ring[s][drow][dpc8 * 8]);
    int stepl = g * 8 + s;
    int t = rev ? 63 - stepl : stepl;
    *(bf16x8*)(hout + ((size_t)(seq0 + drow) * 64 + t) * 128 + dchunk * 8) = v;
  };

  const int swz = (l15 >> 2) & 3;

  // Accumulators live across the barrier: at the top of step t they hold
  // bias + x(t)@Wih (computed during step t-1's gate phase).
  f32x4 acc[2][4];

  auto ih_accum = [&](bf16x8 (&ax)[2][4]) {
    #pragma unroll
    for (int mt = 0; mt < 2; ++mt)
      #pragma unroll
      for (int g = 0; g < 4; ++g) {
        f32x4 bs = {bia[g], bia[g], bia[g], bia[g]};   // bias folded into C
        acc[mt][g] = bs;
      }
    #pragma unroll
    for (int kc = 0; kc < 4; ++kc)
      #pragma unroll
      for (int mt = 0; mt < 2; ++mt)
        #pragma unroll
        for (int g = 0; g < 4; ++g)
          acc[mt][g] = __builtin_amdgcn_mfma_f32_16x16x32_bf16(ax[mt][kc], Bih[g][kc], acc[mt][g], 0, 0, 0);
  };

  auto do_step = [&](int step, bf16x8 (&axc)[2][4], bf16x8 (&axn)[2][4]) {
    (void)axc;  // x(t) already folded into acc via ih_accum last step
    // --- prefetch x(t+1) (issued first; completes during gate math) ---
    const int tn_l = (step < 63) ? step + 1 : 63;
    const int tn   = rev ? 63 - tn_l : tn_l;
    #pragma unroll
    for (int mt = 0; mt < 2; ++mt)
      #pragma unroll
      for (int kc = 0; kc < 4; ++kc)
        axn[mt][kc] = *(const bf16x8*)(xn + xbase[mt] + tn * tstride + kc * 32 + l4 * 8);

    // --- lazy dump: slot (step+1)&7 of group ((step+1)>>3)-1.
    // Written at 8g+s, read here at 8g+s+7, rewritten at 8g+s+8 (post-barrier).
    if (step >= 7) dump_slot(((step + 1) >> 3) - 1, (step + 1) & 7);

    // --- hh MFMAs: only 4-deep chains on the barrier-locked critical path ---
    const int prev = (step + 7) & 7;
    #pragma unroll
    for (int kc = 0; kc < 4; ++kc) {
      bf16x8 ah[2];
      #pragma unroll
      for (int mt = 0; mt < 2; ++mt)
        ah[mt] = *(const bf16x8*)(&ring[prev][mt * 16 + l15][((kc * 4 + l4) ^ swz) * 8]);
      #pragma unroll
      for (int mt = 0; mt < 2; ++mt)
        #pragma unroll
        for (int g = 0; g < 4; ++g)
          acc[mt][g] = __builtin_amdgcn_mfma_f32_16x16x32_bf16(ah[mt], Bhh[g][kc], acc[mt][g], 0, 0, 0);
    }

    // gate math. D layout: col = lane&15 (= channel mycol), row = l4*4+r (= seq)
    const int slot = step & 7;
    #pragma unroll
    for (int mt = 0; mt < 2; ++mt)
      #pragma unroll
      for (int r = 0; r < 4; ++r) {
        float zi = acc[mt][0][r];
        float zf = acc[mt][1][r];
        float zg = acc[mt][2][r];
        float zo = acc[mt][3][r];
        float c = sigf(zf) * cst[mt][r] + sigf(zi) * tanh2s(zg);
        cst[mt][r] = c;
        float h = sigf(zo) * tanh2s(c);
        int row = mt * 16 + l4 * 4 + r;
        ring[slot][row][((mycol >> 3) ^ l4) * 8 + (mycol & 7)] = f2bf(h);
      }

    // --- pipelined ih projection for t+1: no dependence on h(t), so the
    // scheduler interleaves these MFMAs with the gate VALU/TRANS stream ---
    if (step < 63) ih_accum(axn);

    // Raw barrier: LDS ordering only. No vmcnt/expcnt drain (dump store has
    // no in-kernel reader; prefetch loads are private to the issuing wave).
    asm volatile("s_waitcnt lgkmcnt(0)" ::: "memory");
    __builtin_amdgcn_s_barrier();
    __builtin_amdgcn_sched_barrier(0);
  };

  // preload x(t0), then acc = bias + ih(t0); run 64 steps, x double-buffered
  bf16x8 axA[2][4], axB[2][4];
  {
    const int t0 = rev ? 63 : 0;
    #pragma unroll
    for (int mt = 0; mt < 2; ++mt)
      #pragma unroll
      for (int kc = 0; kc < 4; ++kc)
        axA[mt][kc] = *(const bf16x8*)(xn + xbase[mt] + t0 * tstride + kc * 32 + l4 * 8);
  }
  ih_accum(axA);
  for (int s2 = 0; s2 < 64; s2 += 2) {
    do_step(s2,     axA, axB);
    do_step(s2 + 1, axB, axA);
  }
  // remaining slots of the last group (reads fenced by the final barrier)
  #pragma unroll
  for (int s = 1; s < 8; ++s) dump_slot(7, s);
}

// ---------------------------------------------------------------------------
// Kernel 4: 1x1 conv = [128 pixels x 128 ch] x [128 ch x 128 out] MFMA GEMM.
//   grid (1024, 4): blockIdx.y = output {0:down, 1:up, 2:right, 3:left}
//   Two-pass epilogue through a 33KB LDS tile (64 o-rows per pass) -> more
//   blocks/CU than the old 64KB single-pass transpose.
// ---------------------------------------------------------------------------
__global__ __launch_bounds__(256, 2) void conv_kernel(
    const uint16_t* __restrict__ hbuf, const uint16_t* __restrict__ wc,
    const float* __restrict__ b_down, const float* __restrict__ b_up,
    const float* __restrict__ b_right, const float* __restrict__ b_left,
    float* __restrict__ out)
{
  const int d   = blockIdx.y;
  const int P0  = blockIdx.x * 128;
  const int tid = threadIdx.x;
  const int wv = tid >> 6, lane = tid & 63, l15 = lane & 15, l4 = lane >> 4;

  const int lstm_dir = (d == 0) ? 1 : (d == 1) ? 0 : d;   // down<-v_bwd, up<-v_fwd
  const uint16_t* hb = hbuf + (size_t)lstm_dir * ((size_t)2048 * 64 * 128);
  const uint16_t* w  = wc + d * (128 * 128);
  const float* bias = (d == 0) ? b_down : (d == 1) ? b_up : (d == 2) ? b_right : b_left;
  float* outp = out + (size_t)d * OUTSZ;

  bf16x8 Bf[2][4];
  float bc[2];
  #pragma unroll
  for (int j = 0; j < 2; ++j) {
    int o = (2 * wv + j) * 16 + l15;
    bc[j] = bias[o];
    #pragma unroll
    for (int kc = 0; kc < 4; ++kc)
      Bf[j][kc] = *(const bf16x8*)(w + o * 128 + kc * 32 + l4 * 8);
  }

  const f32x4 vzero = {0.f, 0.f, 0.f, 0.f};
  f32x4 acc[8][2];
  #pragma unroll
  for (int mt = 0; mt < 8; ++mt) { acc[mt][0] = vzero; acc[mt][1] = vzero; }

  #pragma unroll
  for (int kc = 0; kc < 4; ++kc) {
    bf16x8 A[8];
    #pragma unroll
    for (int mt = 0; mt < 8; ++mt) {
      int p = P0 + mt * 16 + l15;
      A[mt] = *(const bf16x8*)(hb + (size_t)p * 128 + kc * 32 + l4 * 8);
    }
    #pragma unroll
    for (int mt = 0; mt < 8; ++mt)
      #pragma unroll
      for (int j = 0; j < 2; ++j)
        acc[mt][j] = __builtin_amdgcn_mfma_f32_16x16x32_bf16(A[mt], Bf[j][kc], acc[mt][j], 0, 0, 0);
  }

  // Two-pass LDS transpose: pass j handles o-rows (2wv+j)*16+l15 (64 rows).
  // Row stride 132 dwords (%32==4) spreads banks; b128 ops stay width-bound.
  __shared__ __attribute__((aligned(16))) float olds[64][132];
  const int bb = P0 >> 12, s0 = P0 & 4095;
  float* obase = outp + ((size_t)bb * 128) * 4096 + s0;

  #pragma unroll
  for (int j = 0; j < 2; ++j) {
    if (j) __syncthreads();
    #pragma unroll
    for (int mt = 0; mt < 8; ++mt) {
      f32x4 v = acc[mt][j] + bc[j];
      *(f32x4*)(&olds[wv * 16 + l15][(mt * 4 + l4) * 4]) = v;
    }
    __syncthreads();
    #pragma unroll
    for (int it = 0; it < 8; ++it) {
      int flat = (it * 256 + tid) * 4;
      int ol = flat >> 7, s = flat & 127;
      int o = (ol >> 4) * 32 + j * 16 + (ol & 15);
      f32x4 v = *(const f32x4*)(&olds[ol][s]);
      *(f32x4*)(obase + (size_t)o * 4096 + s) = v;   // coalesced fp32 rows
    }
  }
}

// ---------------------------------------------------------------------------
extern "C" void kernel_launch(void* const* d_in, const int* in_sizes, int n_in,
                              void* d_out, int out_size, void* d_ws, size_t ws_size,
                              hipStream_t stream) {
  const float* x = (const float*)d_in[0];
  uint16_t* ws    = (uint16_t*)d_ws;
  uint16_t* xn    = ws;                      // 16,777,216 bf16
  uint16_t* wbuf  = xn + 16777216;           // 524,288 bf16 (8 LSTM mats)
  uint16_t* wcbuf = wbuf + 524288;           // 65,536 bf16 (4 conv mats)
  uint16_t* hbuf  = wcbuf + 65536;           // 4 * 16,777,216 bf16

  transpose_x<<<dim3(64, 32), 256, 0, stream>>>(x, xn);

  PrepArgs pa;
  const int widx[12] = {1, 2, 4, 5, 7, 8, 10, 11, 13, 15, 17, 19};
  for (int i = 0; i < 12; ++i) pa.s[i] = (const float*)d_in[widx[i]];
  prep_weights<<<2304, 256, 0, stream>>>(pa, wbuf, wcbuf);

  lstm_kernel<<<dim3(64, 4), 512, 0, stream>>>(
      xn, wbuf,
      (const float*)d_in[3], (const float*)d_in[6],
      (const float*)d_in[9], (const float*)d_in[12],
      hbuf);

  conv_kernel<<<dim3(1024, 4), 256, 0, stream>>>(
      hbuf, wcbuf,
      (const float*)d_in[14], (const float*)d_in[16],
      (const float*)d_in[18], (const float*)d_in[20],
      (float*)d_out);
}

// Round 3
// 587.389 us; speedup vs baseline: 1.0196x; 1.0004x over previous
//
#include <hip/hip_runtime.h>
#include <stdint.h>

#define OUTSZ  (32*128*64*64)  // 16777216 elements per output tensor

typedef short bf16x8 __attribute__((ext_vector_type(8)));  // 8 bf16 = 4 VGPRs
typedef float f32x4  __attribute__((ext_vector_type(4)));

__device__ __forceinline__ uint16_t f2bf(float f) {
  union { float f; uint32_t u; } v; v.f = f;
  uint32_t u = v.u;
  u += 0x7fffu + ((u >> 16) & 1u);   // round-to-nearest-even
  return (uint16_t)(u >> 16);
}

__device__ __forceinline__ float sigf(float x) {
  return __builtin_amdgcn_rcpf(1.f + __expf(-x));
}
// tanh(x) = 2*sigmoid(2x) - 1. Saturates correctly via rcp(inf)=0.
__device__ __forceinline__ float tanh2s(float x) {
  float e = __expf(-2.f * x);
  return __builtin_amdgcn_rcpf(1.f + e) * 2.f - 1.f;
}

// ---------------------------------------------------------------------------
// Kernel 1: x [B,C,H,W] fp32 -> x_nhwc [B,H,W,C] bf16   (one block per (b,h))
// ---------------------------------------------------------------------------
__global__ void transpose_x(const float* __restrict__ x, uint16_t* __restrict__ xn) {
  const int h = blockIdx.x, b = blockIdx.y;
  __shared__ float tile[128][65];
  const int tid = threadIdx.x;
  #pragma unroll
  for (int it = 0; it < 32; ++it) {
    int idx = it * 256 + tid;
    int c = idx >> 6, w = idx & 63;
    tile[c][w] = x[(((b * 128 + c) * 64 + h) << 6) + w];  // coalesced in w
  }
  __syncthreads();
  uint32_t* out = (uint32_t*)(xn + ((size_t)(b * 64 + h) * 64) * 128);
  #pragma unroll
  for (int it = 0; it < 16; ++it) {
    int idx = it * 256 + tid;
    int w = idx >> 6, cd = idx & 63;            // cd = pair of channels
    uint32_t lo = f2bf(tile[cd * 2][w]);
    uint32_t hi = f2bf(tile[cd * 2 + 1][w]);
    out[w * 64 + cd] = lo | (hi << 16);          // coalesced in c
  }
}

// ---------------------------------------------------------------------------
// Kernel 2: convert 8 LSTM [512x128] + 4 conv [128x128] weight mats to bf16
// ---------------------------------------------------------------------------
struct PrepArgs { const float* s[12]; };

__global__ void prep_weights(PrepArgs a, uint16_t* __restrict__ wbuf,
                             uint16_t* __restrict__ wcbuf) {
  int idx = blockIdx.x * 256 + threadIdx.x;
  if (idx < 524288) {
    int m = idx >> 16;
    wbuf[idx] = f2bf(a.s[m][idx & 65535]);
  } else {
    int j = idx - 524288;
    if (j < 65536) {
      int m = j >> 14;
      wcbuf[j] = f2bf(a.s[8 + m][j & 16383]);
    }
  }
}

// ---------------------------------------------------------------------------
// Kernel 3: fused bidirectional LSTM over both axes.
//   grid (64, 4): blockIdx.y = dir {0:v_fwd, 1:v_bwd, 2:h_fwd, 3:h_bwd}
//   512 thr = 8 waves, 32 sequences/block, full time loop in-block.
//
//   Occupancy is register-walled at 2 waves/SIMD (Bih+Bhh = 128 regs/lane;
//   combined VGPR+AGPR ~256 vs the 512-reg/SIMD pool), so the only lever is
//   intra-step pipe overlap. Step schedule interleaves independent MFMA and
//   VALU streams:
//     P1: hh(mt=0) MFMA
//     P2: hh(mt=1) MFMA  ||  gate math mt=0  (independent)
//     P3: ih(t+1, mt=0)  ||  gate math mt=1 + lazy dump
//     P4: ih(t+1, mt=1)  ||  ring writes / loop overhead
//   Bias lives in persistent splat registers used as the C operand of the
//   first ih MFMA (no per-step accumulator re-init). h->bf16 via
//   v_cvt_pk_bf16_f32 (RNE, bit-identical to f2bf).
// ---------------------------------------------------------------------------
__global__ __launch_bounds__(512, 2) void lstm_kernel(
    const uint16_t* __restrict__ xn,    // [PIXTOT][128] bf16 NHWC
    const uint16_t* __restrict__ wbuf,  // 8 x [512][128] bf16
    const float* __restrict__ bvf, const float* __restrict__ bvb,
    const float* __restrict__ bhf, const float* __restrict__ bhb,
    uint16_t* __restrict__ hbuf)        // 4 x [2048*64][128] bf16
{
  const int dir  = blockIdx.y;
  const int seq0 = blockIdx.x * 32;
  const int tid  = threadIdx.x;
  const int wv   = tid >> 6;
  const int lane = tid & 63;
  const int l15  = lane & 15;
  const int l4   = lane >> 4;
  const int mycol = wv * 16 + l15;       // channel 0..127 this lane owns in C/D
  const bool rev   = (dir & 1);
  const bool horiz = (dir >= 2);

  const uint16_t* wih = wbuf + (size_t)(2 * dir) * (512 * 128);
  const uint16_t* whh = wih + 512 * 128;
  const float* bias = (dir == 0) ? bvf : (dir == 1) ? bvb : (dir == 2) ? bhf : bhb;
  uint16_t* hout = hbuf + (size_t)dir * ((size_t)2048 * 64 * 128);

  // B fragments: Wih/Whh are [4C][C] row-major = B^T; frag = 8 consecutive c.
  bf16x8 Bih[4][4], Bhh[4][4];           // [gate i/f/g/o][k-chunk]
  {
    const int base = mycol * 128 + l4 * 8;
    #pragma unroll
    for (int g = 0; g < 4; ++g)
      #pragma unroll
      for (int kc = 0; kc < 4; ++kc) {
        Bih[g][kc] = *(const bf16x8*)(wih + base + g * (128 * 128) + kc * 32);
        Bhh[g][kc] = *(const bf16x8*)(whh + base + g * (128 * 128) + kc * 32);
      }
  }
  // persistent bias splats: C operand of the first ih MFMA of each step
  f32x4 biav[4];
  #pragma unroll
  for (int g = 0; g < 4; ++g) {
    float b = bias[mycol + 128 * g];
    f32x4 bs = {b, b, b, b};
    biav[g] = bs;
  }

  // 8-slot h ring. Row stride 136 u16 = 272B (16B aligned). 16B chunks are
  // XOR-swizzled by (row>>2)&3 -> scalar gate writes are bank-conflict-free.
  __shared__ __attribute__((aligned(16))) uint16_t ring[8][32][136];
  {
    uint32_t* p = (uint32_t*)&ring[7][0][0];   // only slot 7 is read at step 0
    for (int i = tid; i < 2176; i += 512) p[i] = 0;
  }
  __syncthreads();

  int xbase[2];
  #pragma unroll
  for (int mt = 0; mt < 2; ++mt) {
    int seq = seq0 + mt * 16 + l15;
    xbase[mt] = horiz ? (((seq >> 6) * 4096 + (seq & 63)) * 128)
                      : (seq * (64 * 128));
  }
  const int tstride = horiz ? (64 * 128) : 128;

  float cst[2][4];
  #pragma unroll
  for (int mt = 0; mt < 2; ++mt)
    #pragma unroll
    for (int r = 0; r < 4; ++r) cst[mt][r] = 0.f;

  // lazy-dump lane mapping: 512 thr cover one slot (32 rows x 16 chunks)
  const int drow   = tid >> 4;          // 0..31
  const int dchunk = tid & 15;
  const int dpc8   = dchunk ^ ((drow >> 2) & 3);

  auto dump_slot = [&](int g, int s) {
    bf16x8 v = *(const bf16x8*)(&ring[s][drow][dpc8 * 8]);
    int stepl = g * 8 + s;
    int t = rev ? 63 - stepl : stepl;
    *(bf16x8*)(hout + ((size_t)(seq0 + drow) * 64 + t) * 128 + dchunk * 8) = v;
  };

  const int swz = (l15 >> 2) & 3;

  // acc holds (bias + x(t)@Wih) at step top; hh accumulates onto it.
  f32x4 acc[2][4];

  auto gate_math = [&](int mt, int slot) {
    float h[4];
    #pragma unroll
    for (int r = 0; r < 4; ++r) {
      float zi = acc[mt][0][r];
      float zf = acc[mt][1][r];
      float zg = acc[mt][2][r];
      float zo = acc[mt][3][r];
      float c = sigf(zf) * cst[mt][r] + sigf(zi) * tanh2s(zg);
      cst[mt][r] = c;
      h[r] = sigf(zo) * tanh2s(c);
    }
    // pack row-pairs: rows mt*16+l4*4+{0,1} and {2,3}; swizzle depends on l4
    // only, so row+1 is exactly +136 u16.
    uint16_t* a0 = &ring[slot][mt * 16 + l4 * 4][((mycol >> 3) ^ l4) * 8 + (mycol & 7)];
    #pragma unroll
    for (int p = 0; p < 2; ++p) {
      uint32_t v;
      asm("v_cvt_pk_bf16_f32 %0, %1, %2" : "=v"(v) : "v"(h[2 * p]), "v"(h[2 * p + 1]));
      uint16_t* ap = a0 + (2 * p) * 136;
      ap[0]   = (uint16_t)v;
      ap[136] = (uint16_t)(v >> 16);
    }
  };

  auto ih_mt = [&](int mt, bf16x8 (&ax)[2][4]) {
    #pragma unroll
    for (int g = 0; g < 4; ++g)
      acc[mt][g] = __builtin_amdgcn_mfma_f32_16x16x32_bf16(ax[mt][0], Bih[g][0], biav[g], 0, 0, 0);
    #pragma unroll
    for (int kc = 1; kc < 4; ++kc)
      #pragma unroll
      for (int g = 0; g < 4; ++g)
        acc[mt][g] = __builtin_amdgcn_mfma_f32_16x16x32_bf16(ax[mt][kc], Bih[g][kc], acc[mt][g], 0, 0, 0);
  };

  auto do_step = [&](int step, bf16x8 (&axc)[2][4], bf16x8 (&axn)[2][4]) {
    (void)axc;  // x(t) already folded into acc via ih of step t-1
    // --- prefetch x(t+1) (issued first; completes during gate math) ---
    const int tn_l = (step < 63) ? step + 1 : 63;
    const int tn   = rev ? 63 - tn_l : tn_l;
    #pragma unroll
    for (int mt = 0; mt < 2; ++mt)
      #pragma unroll
      for (int kc = 0; kc < 4; ++kc)
        axn[mt][kc] = *(const bf16x8*)(xn + xbase[mt] + tn * tstride + kc * 32 + l4 * 8);

    const int prev = (step + 7) & 7;
    const int slot = step & 7;

    // P1: hh MFMA, mt=0 (acc[0] complete after this)
    #pragma unroll
    for (int kc = 0; kc < 4; ++kc) {
      bf16x8 ah = *(const bf16x8*)(&ring[prev][l15][((kc * 4 + l4) ^ swz) * 8]);
      #pragma unroll
      for (int g = 0; g < 4; ++g)
        acc[0][g] = __builtin_amdgcn_mfma_f32_16x16x32_bf16(ah, Bhh[g][kc], acc[0][g], 0, 0, 0);
    }
    // P2: hh MFMA mt=1 — independent of gate(mt=0); scheduler interleaves
    #pragma unroll
    for (int kc = 0; kc < 4; ++kc) {
      bf16x8 ah = *(const bf16x8*)(&ring[prev][16 + l15][((kc * 4 + l4) ^ swz) * 8]);
      #pragma unroll
      for (int g = 0; g < 4; ++g)
        acc[1][g] = __builtin_amdgcn_mfma_f32_16x16x32_bf16(ah, Bhh[g][kc], acc[1][g], 0, 0, 0);
    }
    gate_math(0, slot);

    // lazy dump: slot (step+1)&7 of group ((step+1)>>3)-1; independent filler.
    if (step >= 7) dump_slot(((step + 1) >> 3) - 1, (step + 1) & 7);

    // P3: ih(t+1) mt=0 (re-inits acc[0] via biav C operand) || gate mt=1
    if (step < 63) ih_mt(0, axn);
    gate_math(1, slot);
    // P4: ih(t+1) mt=1 || ring writes + loop overhead
    if (step < 63) ih_mt(1, axn);

    // Raw barrier: LDS ordering only (no vmcnt/expcnt drain).
    asm volatile("s_waitcnt lgkmcnt(0)" ::: "memory");
    __builtin_amdgcn_s_barrier();
    __builtin_amdgcn_sched_barrier(0);
  };

  // preload x(t0), then acc = bias + ih(t0); run 64 steps, x double-buffered
  bf16x8 axA[2][4], axB[2][4];
  {
    const int t0 = rev ? 63 : 0;
    #pragma unroll
    for (int mt = 0; mt < 2; ++mt)
      #pragma unroll
      for (int kc = 0; kc < 4; ++kc)
        axA[mt][kc] = *(const bf16x8*)(xn + xbase[mt] + t0 * tstride + kc * 32 + l4 * 8);
  }
  ih_mt(0, axA);
  ih_mt(1, axA);
  for (int s2 = 0; s2 < 64; s2 += 2) {
    do_step(s2,     axA, axB);
    do_step(s2 + 1, axB, axA);
  }
  // remaining slots of the last group (reads fenced by the final barrier)
  #pragma unroll
  for (int s = 1; s < 8; ++s) dump_slot(7, s);
}

// ---------------------------------------------------------------------------
// Kernel 4: 1x1 conv = [128 pixels x 128 ch] x [128 ch x 128 out] MFMA GEMM.
//   grid (1024, 4): blockIdx.y = output {0:down, 1:up, 2:right, 3:left}
//   Two-pass epilogue through a 33KB LDS tile (64 o-rows per pass) -> more
//   blocks/CU than the old 64KB single-pass transpose.
// ---------------------------------------------------------------------------
__global__ __launch_bounds__(256, 2) void conv_kernel(
    const uint16_t* __restrict__ hbuf, const uint16_t* __restrict__ wc,
    const float* __restrict__ b_down, const float* __restrict__ b_up,
    const float* __restrict__ b_right, const float* __restrict__ b_left,
    float* __restrict__ out)
{
  const int d   = blockIdx.y;
  const int P0  = blockIdx.x * 128;
  const int tid = threadIdx.x;
  const int wv = tid >> 6, lane = tid & 63, l15 = lane & 15, l4 = lane >> 4;

  const int lstm_dir = (d == 0) ? 1 : (d == 1) ? 0 : d;   // down<-v_bwd, up<-v_fwd
  const uint16_t* hb = hbuf + (size_t)lstm_dir * ((size_t)2048 * 64 * 128);
  const uint16_t* w  = wc + d * (128 * 128);
  const float* bias = (d == 0) ? b_down : (d == 1) ? b_up : (d == 2) ? b_right : b_left;
  float* outp = out + (size_t)d * OUTSZ;

  bf16x8 Bf[2][4];
  float bc[2];
  #pragma unroll
  for (int j = 0; j < 2; ++j) {
    int o = (2 * wv + j) * 16 + l15;
    bc[j] = bias[o];
    #pragma unroll
    for (int kc = 0; kc < 4; ++kc)
      Bf[j][kc] = *(const bf16x8*)(w + o * 128 + kc * 32 + l4 * 8);
  }

  const f32x4 vzero = {0.f, 0.f, 0.f, 0.f};
  f32x4 acc[8][2];
  #pragma unroll
  for (int mt = 0; mt < 8; ++mt) { acc[mt][0] = vzero; acc[mt][1] = vzero; }

  #pragma unroll
  for (int kc = 0; kc < 4; ++kc) {
    bf16x8 A[8];
    #pragma unroll
    for (int mt = 0; mt < 8; ++mt) {
      int p = P0 + mt * 16 + l15;
      A[mt] = *(const bf16x8*)(hb + (size_t)p * 128 + kc * 32 + l4 * 8);
    }
    #pragma unroll
    for (int mt = 0; mt < 8; ++mt)
      #pragma unroll
      for (int j = 0; j < 2; ++j)
        acc[mt][j] = __builtin_amdgcn_mfma_f32_16x16x32_bf16(A[mt], Bf[j][kc], acc[mt][j], 0, 0, 0);
  }

  // Two-pass LDS transpose: pass j handles o-rows (2wv+j)*16+l15 (64 rows).
  // Row stride 132 dwords (%32==4) spreads banks; b128 ops stay width-bound.
  __shared__ __attribute__((aligned(16))) float olds[64][132];
  const int bb = P0 >> 12, s0 = P0 & 4095;
  float* obase = outp + ((size_t)bb * 128) * 4096 + s0;

  #pragma unroll
  for (int j = 0; j < 2; ++j) {
    if (j) __syncthreads();
    #pragma unroll
    for (int mt = 0; mt < 8; ++mt) {
      f32x4 v = acc[mt][j] + bc[j];
      *(f32x4*)(&olds[wv * 16 + l15][(mt * 4 + l4) * 4]) = v;
    }
    __syncthreads();
    #pragma unroll
    for (int it = 0; it < 8; ++it) {
      int flat = (it * 256 + tid) * 4;
      int ol = flat >> 7, s = flat & 127;
      int o = (ol >> 4) * 32 + j * 16 + (ol & 15);
      f32x4 v = *(const f32x4*)(&olds[ol][s]);
      *(f32x4*)(obase + (size_t)o * 4096 + s) = v;   // coalesced fp32 rows
    }
  }
}

// ---------------------------------------------------------------------------
extern "C" void kernel_launch(void* const* d_in, const int* in_sizes, int n_in,
                              void* d_out, int out_size, void* d_ws, size_t ws_size,
                              hipStream_t stream) {
  const float* x = (const float*)d_in[0];
  uint16_t* ws    = (uint16_t*)d_ws;
  uint16_t* xn    = ws;                      // 16,777,216 bf16
  uint16_t* wbuf  = xn + 16777216;           // 524,288 bf16 (8 LSTM mats)
  uint16_t* wcbuf = wbuf + 524288;           // 65,536 bf16 (4 conv mats)
  uint16_t* hbuf  = wcbuf + 65536;           // 4 * 16,777,216 bf16

  transpose_x<<<dim3(64, 32), 256, 0, stream>>>(x, xn);

  PrepArgs pa;
  const int widx[12] = {1, 2, 4, 5, 7, 8, 10, 11, 13, 15, 17, 19};
  for (int i = 0; i < 12; ++i) pa.s[i] = (const float*)d_in[widx[i]];
  prep_weights<<<2304, 256, 0, stream>>>(pa, wbuf, wcbuf);

  lstm_kernel<<<dim3(64, 4), 512, 0, stream>>>(
      xn, wbuf,
      (const float*)d_in[3], (const float*)d_in[6],
      (const float*)d_in[9], (const float*)d_in[12],
      hbuf);

  conv_kernel<<<dim3(1024, 4), 256, 0, stream>>>(
      hbuf, wcbuf,
      (const float*)d_in[14], (const float*)d_in[16],
      (const float*)d_in[18], (const float*)d_in[20],
      (float*)d_out);
}